// Round 5
// baseline (5966.986 us; speedup 1.0000x reference)
//
#include <hip/hip_runtime.h>
#include <math.h>

// ---------------- problem constants ----------------
static constexpr int  cB   = 16;
static constexpr int  cS   = 4096;
static constexpr int  cDIN = 64;
static constexpr int  cE   = 512;
static constexpr int  cM   = 128;
static constexpr int  cL   = 4;
static constexpr int  cFF  = 2048;   // 4*E
static constexpr int  cHE  = 256;    // E/2
static constexpr long cNBS = (long)cB * cS;   // 65536 rows

typedef __attribute__((ext_vector_type(8))) short  bf16x8;
typedef __attribute__((ext_vector_type(4))) float  f32x4;

__device__ __forceinline__ float b2f(unsigned short u) {
  union { unsigned int i; float f; } x; x.i = ((unsigned int)u) << 16; return x.f;
}
__device__ __forceinline__ unsigned short f2b(float f) {
  union { float f; unsigned int i; } x; x.f = f;
  unsigned int r = x.i + 0x7FFFu + ((x.i >> 16) & 1u);   // RNE
  return (unsigned short)(r >> 16);
}

// ---------------- GEMM: C[rows x N] = f(alpha*A@Bt^T + bias) -------------
// A: rows x K bf16 row-major. Bt: N x K bf16 row-major (= B^T). Output bf16.
#define FLAG_BIAS    2
#define FLAG_GELU    4
#define FLAG_RES     8    // += bf16 Res[idx]
#define FLAG_VT      16   // store transposed per 4096-row batch: (E x S)
#define FLAG_DEN     32   // *= 1/(aux[zb*rowsPerBatch+rr]+1e-6)
#define FLAG_PHI1    64   // block-max of (alpha*acc - aux[rr]) -> pmax[blockIdx.x]; NO store
#define FLAG_PHI2    128  // exp(alpha*acc - aux[rr] - gmx[0])/sqrt(M)

#define GMT 128
#define GNT 128
#define GBK 32
#define GLROW 40   // 32 + 8 pad; 80B row stride (multiple of 16B)

__global__ __launch_bounds__(256, 2)
void gemm_kernel(const unsigned short* __restrict__ A,
                 const unsigned short* __restrict__ Bt,
                 const unsigned short* __restrict__ bias,
                 const unsigned short* __restrict__ Res,
                 const float* __restrict__ aux,
                 float* __restrict__ pmax,
                 const float* __restrict__ gmx,
                 unsigned short* __restrict__ C,
                 int K, int N, float alpha, int flags,
                 long sA, long sB, long sC)
{
  __shared__ __align__(16) unsigned short As[GMT][GLROW];
  __shared__ __align__(16) unsigned short Bs[GNT][GLROW];
  __shared__ float wred[4];
  const int tid = threadIdx.x;
  const long zb = blockIdx.z;
  const unsigned short* Ab = A + zb * sA + (long)blockIdx.x * GMT * K;
  const unsigned short* Bb = Bt + zb * sB + (long)blockIdx.y * GNT * K;

  const int srow = tid >> 2;          // 0..63
  const int scol = (tid & 3) << 3;    // 0,8,16,24

  const f32x4 fzero = {0.f, 0.f, 0.f, 0.f};
  f32x4 acc[4][4];
#pragma unroll
  for (int i = 0; i < 4; ++i)
#pragma unroll
    for (int j = 0; j < 4; ++j) acc[i][j] = fzero;

  const int wid  = tid >> 6;
  const int lane = tid & 63;
  const int wm   = (wid >> 1) << 6;
  const int wn   = (wid & 1) << 6;
  const int fm   = lane & 15;
  const int kq   = (lane >> 4) << 3;

  for (int k0 = 0; k0 < K; k0 += GBK) {
    const unsigned short* pa = Ab + (long)srow * K + (k0 + scol);
    const unsigned short* pb = Bb + (long)srow * K + (k0 + scol);
    bf16x8 a0 = *(const bf16x8*)pa;
    bf16x8 a1 = *(const bf16x8*)(pa + (long)64 * K);
    bf16x8 b0 = *(const bf16x8*)pb;
    bf16x8 b1 = *(const bf16x8*)(pb + (long)64 * K);
    *(bf16x8*)&As[srow][scol]      = a0;
    *(bf16x8*)&As[srow + 64][scol] = a1;
    *(bf16x8*)&Bs[srow][scol]      = b0;
    *(bf16x8*)&Bs[srow + 64][scol] = b1;
    __syncthreads();

    bf16x8 af[4], bfv[4];
#pragma unroll
    for (int i = 0; i < 4; ++i) {
      af[i]  = *(const bf16x8*)&As[wm + i * 16 + fm][kq];
      bfv[i] = *(const bf16x8*)&Bs[wn + i * 16 + fm][kq];
    }
#pragma unroll
    for (int i = 0; i < 4; ++i)
#pragma unroll
      for (int j = 0; j < 4; ++j)
        acc[i][j] = __builtin_amdgcn_mfma_f32_16x16x32_bf16(af[i], bfv[j], acc[i][j], 0, 0, 0);
    __syncthreads();
  }

  // epilogue: C/D layout col=lane&15, row=(lane>>4)*4+reg  [verified m89/m91]
  const int rq = (lane >> 4) << 2;
  const long crow0 = (long)blockIdx.x * GMT + wm;
  const int  ccol0 = blockIdx.y * GNT + wn;
  const long rowsPerBatch = (long)gridDim.x * GMT;

  if (flags & FLAG_PHI1) {        // max-only pass, no store (batches==1, grid.y==1)
    float mx = -3.0e38f;
#pragma unroll
    for (int i = 0; i < 4; ++i) {
      const long rbase = crow0 + i * 16 + rq;
#pragma unroll
      for (int r = 0; r < 4; ++r) {
        const float rn = aux[rbase + r];
#pragma unroll
        for (int j = 0; j < 4; ++j) mx = fmaxf(mx, acc[i][j][r] * alpha - rn);
      }
    }
#pragma unroll
    for (int off = 32; off >= 1; off >>= 1) mx = fmaxf(mx, __shfl_down(mx, off, 64));
    if (lane == 0) wred[wid] = mx;
    __syncthreads();
    if (tid == 0)
      pmax[blockIdx.x] = fmaxf(fmaxf(wred[0], wred[1]), fmaxf(wred[2], wred[3]));
  } else {
    float gmv = 0.f;
    if (flags & FLAG_PHI2) gmv = gmx[0];

#pragma unroll
    for (int j = 0; j < 4; ++j) {
      const int cc = ccol0 + j * 16 + fm;
      const float bv = (flags & FLAG_BIAS) ? b2f(bias[cc]) : 0.f;
#pragma unroll
      for (int i = 0; i < 4; ++i) {
        const long rbase = crow0 + i * 16 + rq;
#pragma unroll
        for (int r = 0; r < 4; ++r) {
          const long rr = rbase + r;
          float v = acc[i][j][r] * alpha + bv;
          if (flags & FLAG_PHI2)
            v = __expf(fminf(v - aux[rr] - gmv, 0.f)) * 0.08838834764831845f;
          if (flags & FLAG_GELU) v = 0.5f * v * (1.f + erff(v * 0.7071067811865475f));
          if (flags & FLAG_DEN)
            v *= 1.f / (fmaxf(aux[zb * rowsPerBatch + rr], 0.f) + 1e-6f);
          if (flags & FLAG_VT) {
            const long idx = (rr >> 12) * ((long)cE * cS) + (long)cc * cS + (rr & (cS - 1));
            C[idx] = f2b(v);
          } else {
            const long idx = zb * sC + rr * (long)N + cc;
            if (flags & FLAG_RES) v += b2f(Res[idx]);
            C[idx] = f2b(v);
          }
        }
      }
    }
  }
}

// ---------------- dtype shim ----------------
// ln_g[0] == 1.0 exactly. f32 little-endian low ushort = 0x0000 -> flag 1 (f32).
// bf16 -> 0x3F80 -> flag 0 (bf16).
__global__ void detect_kernel(const unsigned short* __restrict__ lng,
                              int* __restrict__ flag) {
  if (threadIdx.x == 0 && blockIdx.x == 0) flag[0] = (lng[0] == 0) ? 1 : 0;
}

// convert one tensor to bf16 (or copy verbatim when already bf16)
__global__ __launch_bounds__(256) void cvt_kernel(const void* __restrict__ in,
                                                  unsigned short* __restrict__ out,
                                                  long n, const int* __restrict__ flag) {
  long i = (long)blockIdx.x * 256 + threadIdx.x;
  if (i >= n) return;
  if (flag[0]) out[i] = f2b(((const float*)in)[i]);
  else         out[i] = ((const unsigned short*)in)[i];
}

// ---------------- small kernels ----------------
__global__ __launch_bounds__(256) void addpos_kernel(unsigned short* __restrict__ h,
                                                     const unsigned short* __restrict__ pos) {
  long i = ((long)blockIdx.x * 256 + threadIdx.x) * 8;
  long se = i % ((long)cS * cE);
  bf16x8 v = *(bf16x8*)&h[i];
  bf16x8 p = *(const bf16x8*)&pos[se];
#pragma unroll
  for (int r = 0; r < 8; ++r)
    v[r] = (short)f2b(b2f((unsigned short)v[r]) + b2f((unsigned short)p[r]));
  *(bf16x8*)&h[i] = v;
}

// rnorm[row] = hs2 * sum(q[row]^2); 4 rows/block (wave per row)
__global__ __launch_bounds__(256) void rnorm_kernel(const unsigned short* __restrict__ X,
                                                    float* __restrict__ rn, float hs2) {
  const int w = threadIdx.x >> 6, lane = threadIdx.x & 63;
  const long row = (long)blockIdx.x * 4 + w;
  bf16x8 q = *(const bf16x8*)&X[row * cE + lane * 8];
  float s = 0.f;
#pragma unroll
  for (int t = 0; t < 8; ++t) { float v = b2f((unsigned short)q[t]); s += v * v; }
#pragma unroll
  for (int off = 32; off >= 1; off >>= 1) s += __shfl_down(s, off, 64);
  if (lane == 0) rn[row] = hs2 * s;
}

// gmax[0] = max(partials[0..n)); single block
__global__ __launch_bounds__(256) void reducemax_kernel(const float* __restrict__ partials,
                                                        float* __restrict__ gmax, int n) {
  __shared__ float sm[4];
  float mx = -3.0e38f;
  for (int i = threadIdx.x; i < n; i += 256) mx = fmaxf(mx, partials[i]);
#pragma unroll
  for (int off = 32; off >= 1; off >>= 1) mx = fmaxf(mx, __shfl_down(mx, off, 64));
  const int w = threadIdx.x >> 6, lane = threadIdx.x & 63;
  if (lane == 0) sm[w] = mx;
  __syncthreads();
  if (threadIdx.x == 0) gmax[0] = fmaxf(fmaxf(sm[0], sm[1]), fmaxf(sm[2], sm[3]));
}

// z[b][m] = sum_s qtb[b][m][s]   (qtb is B x M x S)
__global__ __launch_bounds__(256) void zsumt_kernel(const unsigned short* __restrict__ qtb,
                                                    float* __restrict__ z) {
  __shared__ float sred[4];
  const int b = blockIdx.x, m = blockIdx.y, tid = threadIdx.x;
  const unsigned short* p = qtb + ((long)b * cM + m) * cS + (long)tid * 16;
  bf16x8 a = *(const bf16x8*)p;
  bf16x8 c = *(const bf16x8*)(p + 8);
  float s = 0.f;
#pragma unroll
  for (int t = 0; t < 8; ++t) s += b2f((unsigned short)a[t]) + b2f((unsigned short)c[t]);
#pragma unroll
  for (int off = 32; off >= 1; off >>= 1) s += __shfl_down(s, off, 64);
  const int w = tid >> 6, lane = tid & 63;
  if (lane == 0) sred[w] = s;
  __syncthreads();
  if (tid == 0) z[b * cM + m] = sred[0] + sred[1] + sred[2] + sred[3];
}

// den[row] = dot(pq[row,:], z[b,:]); 4 rows/block
__global__ __launch_bounds__(256) void den_kernel(const unsigned short* __restrict__ P,
                                                  const float* __restrict__ z,
                                                  float* __restrict__ den) {
  const int w = threadIdx.x >> 6, lane = threadIdx.x & 63;
  const long row = (long)blockIdx.x * 4 + w;
  const float* zb = z + (row >> 12) * cM;
  const unsigned short* p = P + row * cM;
  float d = b2f(p[lane]) * zb[lane] + b2f(p[lane + 64]) * zb[lane + 64];
#pragma unroll
  for (int off = 32; off >= 1; off >>= 1) d += __shfl_down(d, off, 64);
  if (lane == 0) den[row] = d;
}

// layernorm in place (bf16 -> bf16), one row per block
__global__ __launch_bounds__(256) void ln_kernel(unsigned short* __restrict__ a,
                                                 const unsigned short* __restrict__ g,
                                                 const unsigned short* __restrict__ bb) {
  __shared__ float sred[8];
  const long row = blockIdx.x;
  unsigned short* ar = a + row * cE;
  const int tid = threadIdx.x;
  float v0 = b2f(ar[tid]), v1 = b2f(ar[tid + 256]);
  float s = v0 + v1, sq = v0 * v0 + v1 * v1;
#pragma unroll
  for (int off = 32; off >= 1; off >>= 1) {
    s  += __shfl_down(s, off, 64);
    sq += __shfl_down(sq, off, 64);
  }
  const int w = tid >> 6, lane = tid & 63;
  if (lane == 0) { sred[w] = s; sred[4 + w] = sq; }
  __syncthreads();
  const float st  = sred[0] + sred[1] + sred[2] + sred[3];
  const float sqt = sred[4] + sred[5] + sred[6] + sred[7];
  const float mean = st * (1.f / 512.f);
  const float var  = fmaxf(sqt * (1.f / 512.f) - mean * mean, 0.f);
  const float rstd = rsqrtf(var + 1e-5f);
  ar[tid]       = f2b((v0 - mean) * rstd * b2f(g[tid])       + b2f(bb[tid]));
  ar[tid + 256] = f2b((v1 - mean) * rstd * b2f(g[tid + 256]) + b2f(bb[tid + 256]));
}

// batched bf16 transpose: in (R x C) -> out (C x R); grid (C/32, R/32, batch)
__global__ __launch_bounds__(256) void transpose_kernel(const unsigned short* __restrict__ in,
                                                        unsigned short* __restrict__ out,
                                                        int R, int C, long sIn, long sOut) {
  __shared__ unsigned short t[32][33];
  in  += (long)blockIdx.z * sIn;
  out += (long)blockIdx.z * sOut;
  const int bx = blockIdx.x << 5, by = blockIdx.y << 5;
  const int tx = threadIdx.x & 31, ty = threadIdx.x >> 5;
#pragma unroll
  for (int i = ty; i < 32; i += 8) t[i][tx] = in[(long)(by + i) * C + bx + tx];
  __syncthreads();
#pragma unroll
  for (int i = ty; i < 32; i += 8) out[(long)(bx + i) * R + by + tx] = t[tx][i];
}

// final head: out[b] = relu(h[b,0,:]@Wr1+br1)@Wr2+br2 ; grid 16, block 256
__global__ __launch_bounds__(256) void head_kernel(const unsigned short* __restrict__ h,
                                                   const unsigned short* __restrict__ Wr1,
                                                   const unsigned short* __restrict__ br1,
                                                   const unsigned short* __restrict__ Wr2,
                                                   const unsigned short* __restrict__ br2,
                                                   void* __restrict__ out,
                                                   const int* __restrict__ flag) {
  __shared__ float pooled[cE];
  __shared__ float red[4];
  const int b = blockIdx.x, tid = threadIdx.x;
  pooled[tid]       = b2f(h[(long)b * cS * cE + tid]);
  pooled[tid + 256] = b2f(h[(long)b * cS * cE + tid + 256]);
  __syncthreads();
  float acc = b2f(br1[tid]);
  for (int e = 0; e < cE; ++e) acc += pooled[e] * b2f(Wr1[e * cHE + tid]);
  acc = fmaxf(acc, 0.f) * b2f(Wr2[tid]);
#pragma unroll
  for (int off = 32; off >= 1; off >>= 1) acc += __shfl_down(acc, off, 64);
  const int w = tid >> 6, lane = tid & 63;
  if (lane == 0) red[w] = acc;
  __syncthreads();
  if (tid == 0) {
    float r = red[0] + red[1] + red[2] + red[3] + b2f(br2[0]);
    if (flag[0]) ((float*)out)[b] = r;
    else         ((unsigned short*)out)[b] = f2b(r);
  }
}

// ---------------- host ----------------
extern "C" void kernel_launch(void* const* d_in, const int* in_sizes, int n_in,
                              void* d_out, int out_size, void* d_ws, size_t ws_size,
                              hipStream_t stream) {
  (void)in_sizes; (void)n_in; (void)out_size;

  char* ws = (char*)d_ws;
  size_t off = 0;
  auto alloc = [&](size_t bytes) -> void* {
    void* p = ws + off;
    off += (bytes + 255) & ~(size_t)255;
    return p;
  };
  // ---- memory plan (~236 MiB total) ----
  unsigned short* h   = (unsigned short*)alloc(cNBS * cE * 2);   // 67 MB residual (bf16)
  unsigned short* X   = (unsigned short*)alloc(cNBS * cE * 2);   // 67 MB: wstage -> q/k -> qtb -> att -> u1
  unsigned short* Y   = (unsigned short*)alloc(cNBS * cE * 2);   // 67 MB: xb/posb -> phik-tmp -> v^T -> a/y
  unsigned short* Pb  = (unsigned short*)alloc(cNBS * cM * 2);   // 16.8 MB phi(q)
  unsigned short* kvtb= (unsigned short*)alloc((long)cB * cE * cM * 2); // 2.1 MB
  float* vec64k       = (float*)alloc(cNBS * 4);                 // rnorm, then den
  float* z            = (float*)alloc(cB * cM * 4);
  float* partials     = (float*)alloc(512 * 4);
  float* gmaxf        = (float*)alloc(256);
  int*   dflag        = (int*)alloc(256);
  unsigned short* WiT = (unsigned short*)alloc((long)cE * cDIN * 2);
  unsigned short* WqT = (unsigned short*)alloc((long)cL * cE * cE * 2);
  unsigned short* WkT = (unsigned short*)alloc((long)cL * cE * cE * 2);
  unsigned short* WvT = (unsigned short*)alloc((long)cL * cE * cE * 2);
  unsigned short* WoT = (unsigned short*)alloc((long)cL * cE * cE * 2);
  unsigned short* RT  = (unsigned short*)alloc((long)cL * cM * cE * 2);
  unsigned short* W1T = (unsigned short*)alloc((long)cL * cFF * cE * 2);
  unsigned short* W2T = (unsigned short*)alloc((long)cL * cE * cFF * 2);
  unsigned short* sb  = (unsigned short*)alloc(160000 * 2);      // small converted tensors

  // staging of raw bf16 weights inside X (dead until first q GEMM)
  unsigned short* WqB = X;
  unsigned short* WkB = WqB + (long)cL * cE * cE;
  unsigned short* WvB = WkB + (long)cL * cE * cE;
  unsigned short* WoB = WvB + (long)cL * cE * cE;
  unsigned short* RmB = WoB + (long)cL * cE * cE;
  unsigned short* W1B = RmB + (long)cL * cE * cM;
  unsigned short* W2B = W1B + (long)cL * cE * cFF;
  unsigned short* WiB = W2B + (long)cL * cE * cFF;
  // staging of x, pos inside Y (dead until phi(k) tmp)
  unsigned short* xb   = Y;
  unsigned short* posb = Y + cNBS * cDIN;
  // small tensors inside sb
  unsigned short* biC  = sb;                 // 512
  unsigned short* bqC  = biC  + 512;         // 2048
  unsigned short* bkC  = bqC  + 2048;
  unsigned short* bvC  = bkC  + 2048;
  unsigned short* boC  = bvC  + 2048;
  unsigned short* b1C  = boC  + 2048;        // 8192
  unsigned short* b2C  = b1C  + 8192;        // 2048
  unsigned short* lngC = b2C  + 2048;        // 2048
  unsigned short* lnbC = lngC + 2048;        // 2048
  unsigned short* Wr1C = lnbC + 2048;        // 131072
  unsigned short* br1C = Wr1C + 131072;      // 256
  unsigned short* Wr2C = br1C + 256;         // 256
  unsigned short* br2C = Wr2C + 256;         // 1

  unsigned short* qtb  = X;   // pk^T (B x M x S) after k dead
  unsigned short* ytmp = Y;   // phi(k) row-major (B*S x M)
  unsigned short* vtb  = Y;   // v^T (B x E x S)
  unsigned short* attb = X;   // att output
  unsigned short* ab   = Y;   // a / y (LN in place)
  unsigned short* u1b  = X;   // FFN hidden chunk (8192 x 2048)

  if (off > ws_size) return;  // diagnostic fallback: fail absmax instead of faulting

  // ---- dtype detect + convert all inputs to bf16 ----
  detect_kernel<<<1, 64, 0, stream>>>((const unsigned short*)d_in[13], dflag);
  auto cvt = [&](const void* src, unsigned short* dst, long n) {
    cvt_kernel<<<(unsigned)((n + 255) / 256), 256, 0, stream>>>(src, dst, n, dflag);
  };
  cvt(d_in[0],  xb,   cNBS * cDIN);
  cvt(d_in[1],  WiB,  (long)cDIN * cE);
  cvt(d_in[2],  biC,  cE);
  cvt(d_in[3],  posb, (long)cS * cE);
  cvt(d_in[4],  WqB,  (long)cL * cE * cE);
  cvt(d_in[5],  bqC,  (long)cL * cE);
  cvt(d_in[6],  WkB,  (long)cL * cE * cE);
  cvt(d_in[7],  bkC,  (long)cL * cE);
  cvt(d_in[8],  WvB,  (long)cL * cE * cE);
  cvt(d_in[9],  bvC,  (long)cL * cE);
  cvt(d_in[10], WoB,  (long)cL * cE * cE);
  cvt(d_in[11], boC,  (long)cL * cE);
  cvt(d_in[12], RmB,  (long)cL * cE * cM);
  cvt(d_in[13], lngC, (long)cL * cE);
  cvt(d_in[14], lnbC, (long)cL * cE);
  cvt(d_in[15], W1B,  (long)cL * cE * cFF);
  cvt(d_in[16], b1C,  (long)cL * cFF);
  cvt(d_in[17], W2B,  (long)cL * cFF * cE);
  cvt(d_in[18], b2C,  (long)cL * cE);
  cvt(d_in[19], Wr1C, (long)cE * cHE);
  cvt(d_in[20], br1C, cHE);
  cvt(d_in[21], Wr2C, cHE);
  cvt(d_in[22], br2C, 1);

  typedef const unsigned short* cus;
  auto gemm = [&](const void* A, const void* Bt, const void* bias_, const void* Res_,
                  const float* aux_, float* pmax_, const float* gmx_, void* C,
                  long rows, int K, int N, float alpha, int flags,
                  long sA, long sB, long sC, int batches) {
    dim3 g((unsigned)(rows / 128), (unsigned)(N / 128), (unsigned)batches);
    gemm_kernel<<<g, dim3(256), 0, stream>>>(
        (const unsigned short*)A, (const unsigned short*)Bt,
        (const unsigned short*)bias_, (const unsigned short*)Res_,
        aux_, pmax_, gmx_, (unsigned short*)C, K, N, alpha, flags, sA, sB, sC);
  };

  // ---- weight pre-transposes (from bf16 staged copies) ----
  transpose_kernel<<<dim3(16, 2, 1), 256, 0, stream>>>(WiB, WiT, cDIN, cE, 0, 0);
  transpose_kernel<<<dim3(16, 16, cL), 256, 0, stream>>>(WqB, WqT, cE, cE, (long)cE * cE, (long)cE * cE);
  transpose_kernel<<<dim3(16, 16, cL), 256, 0, stream>>>(WkB, WkT, cE, cE, (long)cE * cE, (long)cE * cE);
  transpose_kernel<<<dim3(16, 16, cL), 256, 0, stream>>>(WvB, WvT, cE, cE, (long)cE * cE, (long)cE * cE);
  transpose_kernel<<<dim3(16, 16, cL), 256, 0, stream>>>(WoB, WoT, cE, cE, (long)cE * cE, (long)cE * cE);
  transpose_kernel<<<dim3(4, 16, cL), 256, 0, stream>>>(RmB, RT, cE, cM, (long)cE * cM, (long)cE * cM);
  transpose_kernel<<<dim3(64, 16, cL), 256, 0, stream>>>(W1B, W1T, cE, cFF, (long)cE * cFF, (long)cE * cFF);
  transpose_kernel<<<dim3(16, 64, cL), 256, 0, stream>>>(W2B, W2T, cFF, cE, (long)cFF * cE, (long)cFF * cE);

  // ---- input projection (bf16 h) + positional embedding ----
  gemm(xb, WiT, biC, nullptr, nullptr, nullptr, nullptr, h, cNBS, cDIN, cE, 1.f,
       FLAG_BIAS, 0, 0, 0, 1);
  addpos_kernel<<<16384, 256, 0, stream>>>(h, posb);

  const float scale      = 0.21022410381342863f;    // 512^-0.25
  const float halfscale2 = 0.022097086912079608f;   // 0.5 * 512^-0.5

  for (int i = 0; i < cL; ++i) {
    cus WqT_i = WqT + (long)i * cE * cE;  cus bq_i = bqC + (long)i * cE;
    cus WkT_i = WkT + (long)i * cE * cE;  cus bk_i = bkC + (long)i * cE;
    cus WvT_i = WvT + (long)i * cE * cE;  cus bv_i = bvC + (long)i * cE;
    cus WoT_i = WoT + (long)i * cE * cE;  cus bo_i = boC + (long)i * cE;
    cus RT_i  = RT  + (long)i * cM * cE;
    cus g_i   = lngC + (long)i * cE;      cus b_i  = lnbC + (long)i * cE;
    cus W1T_i = W1T + (long)i * cFF * cE; cus b1_i = b1C + (long)i * cFF;
    cus W2T_i = W2T + (long)i * cE * cFF; cus b2_i = b2C + (long)i * cE;

    // --- phi(q): q -> X; rownorm; two-pass max; Pb = phi(q) ---
    gemm(h, WqT_i, bq_i, nullptr, nullptr, nullptr, nullptr, X, cNBS, cE, cE, 1.f,
         FLAG_BIAS, 0, 0, 0, 1);
    rnorm_kernel<<<16384, 256, 0, stream>>>(X, vec64k, halfscale2);
    gemm(X, RT_i, nullptr, nullptr, vec64k, partials, nullptr, Pb, cNBS, cE, cM, scale,
         FLAG_PHI1, 0, 0, 0, 1);
    reducemax_kernel<<<1, 256, 0, stream>>>(partials, gmaxf, 512);
    gemm(X, RT_i, nullptr, nullptr, vec64k, nullptr, gmaxf, Pb, cNBS, cE, cM, scale,
         FLAG_PHI2, 0, 0, 0, 1);

    // --- phi(k): k -> X; phi(k) -> ytmp (Y); transpose -> qtb (X) ---
    gemm(h, WkT_i, bk_i, nullptr, nullptr, nullptr, nullptr, X, cNBS, cE, cE, 1.f,
         FLAG_BIAS, 0, 0, 0, 1);
    rnorm_kernel<<<16384, 256, 0, stream>>>(X, vec64k, halfscale2);
    gemm(X, RT_i, nullptr, nullptr, vec64k, partials, nullptr, ytmp, cNBS, cE, cM, scale,
         FLAG_PHI1, 0, 0, 0, 1);
    reducemax_kernel<<<1, 256, 0, stream>>>(partials, gmaxf, 512);
    gemm(X, RT_i, nullptr, nullptr, vec64k, nullptr, gmaxf, ytmp, cNBS, cE, cM, scale,
         FLAG_PHI2, 0, 0, 0, 1);
    transpose_kernel<<<dim3(4, 128, cB), 256, 0, stream>>>(ytmp, qtb, cS, cM,
                                                           (long)cS * cM, (long)cS * cM);

    // --- v projection stored directly transposed: vtb (Y) = v^T (B x E x S) ---
    gemm(h, WvT_i, bv_i, nullptr, nullptr, nullptr, nullptr, vtb, cNBS, cE, cE, 1.f,
         FLAG_BIAS | FLAG_VT, 0, 0, 0, 1);

    // --- z, den ---
    zsumt_kernel<<<dim3(cB, cM), 256, 0, stream>>>(qtb, z);
    den_kernel<<<16384, 256, 0, stream>>>(Pb, z, vec64k);

    // --- kv^T[b] (E x M) = v^T[b] (E x S) @ pk[b] (S x M) ---
    gemm(vtb, qtb, nullptr, nullptr, nullptr, nullptr, nullptr, kvtb, cE, cS, cM, 1.f,
         0, (long)cE * cS, (long)cM * cS, (long)cE * cM, cB);
    // --- att[b] (S x E) = (pq[b] @ kv[b]) / (den+1e-6) -> X ---
    gemm(Pb, kvtb, nullptr, nullptr, vec64k, nullptr, nullptr, attb, cS, cM, cE, 1.f,
         FLAG_DEN, (long)cS * cM, (long)cE * cM, (long)cS * cE, cB);

    // --- a = att @ Wo + bo -> Y ; LN in place ---
    gemm(attb, WoT_i, bo_i, nullptr, nullptr, nullptr, nullptr, ab, cNBS, cE, cE, 1.f,
         FLAG_BIAS, 0, 0, 0, 1);
    ln_kernel<<<cNBS, 256, 0, stream>>>(ab, g_i, b_i);

    // --- FFN in 8 row-chunks of 8192; h += ffn(y) ---
    for (int c = 0; c < 8; ++c) {
      const unsigned short* yc = ab + (long)c * 8192 * cE;
      unsigned short* hc = h + (long)c * 8192 * cE;
      gemm(yc, W1T_i, b1_i, nullptr, nullptr, nullptr, nullptr, u1b, 8192, cE, cFF, 1.f,
           FLAG_BIAS | FLAG_GELU, 0, 0, 0, 1);
      gemm(u1b, W2T_i, b2_i, hc, nullptr, nullptr, nullptr, hc, 8192, cFF, cE, 1.f,
           FLAG_BIAS | FLAG_RES, 0, 0, 0, 1);
    }
  }

  head_kernel<<<cB, 256, 0, stream>>>(h, Wr1C, br1C, Wr2C, br2C, d_out, dflag);
}

// Round 6
// 5762.784 us; speedup vs baseline: 1.0354x; 1.0354x over previous
//
#include <hip/hip_runtime.h>
#include <math.h>

// ---------------- problem constants ----------------
static constexpr int  cB   = 16;
static constexpr int  cS   = 4096;
static constexpr int  cDIN = 64;
static constexpr int  cE   = 512;
static constexpr int  cM   = 128;
static constexpr int  cL   = 4;
static constexpr int  cFF  = 2048;   // 4*E
static constexpr int  cHE  = 256;    // E/2
static constexpr long cNBS = (long)cB * cS;   // 65536 rows

typedef __attribute__((ext_vector_type(8))) short  bf16x8;
typedef __attribute__((ext_vector_type(4))) float  f32x4;

typedef const __attribute__((address_space(1))) unsigned int g_u32;
typedef __attribute__((address_space(3))) unsigned int l_u32;

__device__ __forceinline__ float b2f(unsigned short u) {
  union { unsigned int i; float f; } x; x.i = ((unsigned int)u) << 16; return x.f;
}
__device__ __forceinline__ unsigned short f2b(float f) {
  union { float f; unsigned int i; } x; x.f = f;
  unsigned int r = x.i + 0x7FFFu + ((x.i >> 16) & 1u);   // RNE
  return (unsigned short)(r >> 16);
}

// ---------------- GEMM: C[rows x N] = f(alpha*A@Bt^T + bias) -------------
// A: rows x K bf16 row-major. Bt: N x K bf16 row-major (= B^T). Output bf16.
#define FLAG_BIAS    2
#define FLAG_GELU    4
#define FLAG_RES     8    // += bf16 Res[idx]
#define FLAG_VT      16   // store transposed per 4096-row batch: (E x S)
#define FLAG_DEN     32   // *= 1/(aux[zb*rowsPerBatch+rr]+1e-6)
#define FLAG_PHI1    64   // block-max of (alpha*acc - aux[rr]) -> pmax[blockIdx.x]; NO store
#define FLAG_PHI2    128  // exp(alpha*acc - aux[rr] - gmx[0])/sqrt(M)

#define GMT 128
#define GNT 128
#define GBK 32

__global__ __launch_bounds__(256, 2)
void gemm_kernel(const unsigned short* __restrict__ A,
                 const unsigned short* __restrict__ Bt,
                 const unsigned short* __restrict__ bias,
                 const unsigned short* __restrict__ Res,
                 const float* __restrict__ aux,
                 float* __restrict__ pmax,
                 const float* __restrict__ gmx,
                 unsigned short* __restrict__ C,
                 int K, int N, float alpha, int flags,
                 long sA, long sB, long sC)
{
  // unpadded: 32 halves = 64B row; fragment reads hit each bank exactly 8x/wave
  __shared__ __align__(16) unsigned short As[GMT][32];
  __shared__ __align__(16) unsigned short Bs[GNT][32];
  __shared__ float wred[4];
  const int tid = threadIdx.x;
  const int lane = tid & 63;
  const int wid  = tid >> 6;
  const long zb = blockIdx.z;
  const unsigned short* Ab = A + zb * sA + (long)blockIdx.x * GMT * K;
  const unsigned short* Bb = Bt + zb * sB + (long)blockIdx.y * GNT * K;

  // async staging: wave wid covers rows [wid*16, wid*16+16) of each 64-row half,
  // lane's LDS dest = tile_base + wid*1024 + lane*16 bytes (lane-contiguous).
  const int srow = wid * 16 + (lane >> 2);   // 0..63
  const int scol = (lane & 3) << 3;          // 0,8,16,24
  const unsigned short* gA = Ab + (long)srow * K + scol;
  const unsigned short* gB = Bb + (long)srow * K + scol;
  l_u32* lA0 = (l_u32*)&As[srow][scol];
  l_u32* lA1 = (l_u32*)&As[srow + 64][scol];
  l_u32* lB0 = (l_u32*)&Bs[srow][scol];
  l_u32* lB1 = (l_u32*)&Bs[srow + 64][scol];

  const f32x4 fzero = {0.f, 0.f, 0.f, 0.f};
  f32x4 acc[4][4];
#pragma unroll
  for (int i = 0; i < 4; ++i)
#pragma unroll
    for (int j = 0; j < 4; ++j) acc[i][j] = fzero;

  const int wm   = (wid >> 1) << 6;
  const int wn   = (wid & 1) << 6;
  const int fm   = lane & 15;
  const int kq   = (lane >> 4) << 3;

  const long kstep64 = (long)64 * K;
  for (int k0 = 0; k0 < K; k0 += GBK) {
    __builtin_amdgcn_global_load_lds((g_u32*)(gA + k0),           lA0, 16, 0, 0);
    __builtin_amdgcn_global_load_lds((g_u32*)(gA + kstep64 + k0), lA1, 16, 0, 0);
    __builtin_amdgcn_global_load_lds((g_u32*)(gB + k0),           lB0, 16, 0, 0);
    __builtin_amdgcn_global_load_lds((g_u32*)(gB + kstep64 + k0), lB1, 16, 0, 0);
    __syncthreads();

    bf16x8 af[4], bfv[4];
#pragma unroll
    for (int i = 0; i < 4; ++i) {
      af[i]  = *(const bf16x8*)&As[wm + i * 16 + fm][kq];
      bfv[i] = *(const bf16x8*)&Bs[wn + i * 16 + fm][kq];
    }
#pragma unroll
    for (int i = 0; i < 4; ++i)
#pragma unroll
      for (int j = 0; j < 4; ++j)
        acc[i][j] = __builtin_amdgcn_mfma_f32_16x16x32_bf16(af[i], bfv[j], acc[i][j], 0, 0, 0);
    __syncthreads();
  }

  // epilogue: C/D layout col=lane&15, row=(lane>>4)*4+reg  [verified m89/m91]
  const int rq = (lane >> 4) << 2;
  const long crow0 = (long)blockIdx.x * GMT + wm;
  const int  ccol0 = blockIdx.y * GNT + wn;
  const long rowsPerBatch = (long)gridDim.x * GMT;

  if (flags & FLAG_PHI1) {        // max-only pass, no store (batches==1, grid.y==1)
    float mx = -3.0e38f;
#pragma unroll
    for (int i = 0; i < 4; ++i) {
      const long rbase = crow0 + i * 16 + rq;
#pragma unroll
      for (int r = 0; r < 4; ++r) {
        const float rn = aux[rbase + r];
#pragma unroll
        for (int j = 0; j < 4; ++j) mx = fmaxf(mx, acc[i][j][r] * alpha - rn);
      }
    }
#pragma unroll
    for (int off = 32; off >= 1; off >>= 1) mx = fmaxf(mx, __shfl_down(mx, off, 64));
    if (lane == 0) wred[wid] = mx;
    __syncthreads();
    if (tid == 0)
      pmax[blockIdx.x] = fmaxf(fmaxf(wred[0], wred[1]), fmaxf(wred[2], wred[3]));
  } else {
    float gmv = 0.f;
    if (flags & FLAG_PHI2) gmv = gmx[0];

#pragma unroll
    for (int j = 0; j < 4; ++j) {
      const int cc = ccol0 + j * 16 + fm;
      const float bv = (flags & FLAG_BIAS) ? b2f(bias[cc]) : 0.f;
#pragma unroll
      for (int i = 0; i < 4; ++i) {
        const long rbase = crow0 + i * 16 + rq;
#pragma unroll
        for (int r = 0; r < 4; ++r) {
          const long rr = rbase + r;
          float v = acc[i][j][r] * alpha + bv;
          if (flags & FLAG_PHI2)
            v = __expf(fminf(v - aux[rr] - gmv, 0.f)) * 0.08838834764831845f;
          if (flags & FLAG_GELU) v = 0.5f * v * (1.f + erff(v * 0.7071067811865475f));
          if (flags & FLAG_DEN)
            v *= 1.f / (fmaxf(aux[zb * rowsPerBatch + rr], 0.f) + 1e-6f);
          if (flags & FLAG_VT) {
            const long idx = (rr >> 12) * ((long)cE * cS) + (long)cc * cS + (rr & (cS - 1));
            C[idx] = f2b(v);
          } else {
            const long idx = zb * sC + rr * (long)N + cc;
            if (flags & FLAG_RES) v += b2f(Res[idx]);
            C[idx] = f2b(v);
          }
        }
      }
    }
  }
}

// ---------------- dtype shim ----------------
// ln_g[0] == 1.0 exactly. f32 little-endian low ushort = 0x0000 -> flag 1 (f32).
__global__ void detect_kernel(const unsigned short* __restrict__ lng,
                              int* __restrict__ flag) {
  if (threadIdx.x == 0 && blockIdx.x == 0) flag[0] = (lng[0] == 0) ? 1 : 0;
}

// convert one tensor to bf16 (or copy verbatim when already bf16)
__global__ __launch_bounds__(256) void cvt_kernel(const void* __restrict__ in,
                                                  unsigned short* __restrict__ out,
                                                  long n, const int* __restrict__ flag) {
  long i = (long)blockIdx.x * 256 + threadIdx.x;
  if (i >= n) return;
  if (flag[0]) out[i] = f2b(((const float*)in)[i]);
  else         out[i] = ((const unsigned short*)in)[i];
}

// ---------------- small kernels ----------------
__global__ __launch_bounds__(256) void addpos_kernel(unsigned short* __restrict__ h,
                                                     const unsigned short* __restrict__ pos) {
  long i = ((long)blockIdx.x * 256 + threadIdx.x) * 8;
  long se = i % ((long)cS * cE);
  bf16x8 v = *(bf16x8*)&h[i];
  bf16x8 p = *(const bf16x8*)&pos[se];
#pragma unroll
  for (int r = 0; r < 8; ++r)
    v[r] = (short)f2b(b2f((unsigned short)v[r]) + b2f((unsigned short)p[r]));
  *(bf16x8*)&h[i] = v;
}

// rnorm[row] = hs2 * sum(q[row]^2); 4 rows/block (wave per row)
__global__ __launch_bounds__(256) void rnorm_kernel(const unsigned short* __restrict__ X,
                                                    float* __restrict__ rn, float hs2) {
  const int w = threadIdx.x >> 6, lane = threadIdx.x & 63;
  const long row = (long)blockIdx.x * 4 + w;
  bf16x8 q = *(const bf16x8*)&X[row * cE + lane * 8];
  float s = 0.f;
#pragma unroll
  for (int t = 0; t < 8; ++t) { float v = b2f((unsigned short)q[t]); s += v * v; }
#pragma unroll
  for (int off = 32; off >= 1; off >>= 1) s += __shfl_down(s, off, 64);
  if (lane == 0) rn[row] = hs2 * s;
}

// gmax[0] = max(partials[0..n)); single block
__global__ __launch_bounds__(256) void reducemax_kernel(const float* __restrict__ partials,
                                                        float* __restrict__ gmax, int n) {
  __shared__ float sm[4];
  float mx = -3.0e38f;
  for (int i = threadIdx.x; i < n; i += 256) mx = fmaxf(mx, partials[i]);
#pragma unroll
  for (int off = 32; off >= 1; off >>= 1) mx = fmaxf(mx, __shfl_down(mx, off, 64));
  const int w = threadIdx.x >> 6, lane = threadIdx.x & 63;
  if (lane == 0) sm[w] = mx;
  __syncthreads();
  if (threadIdx.x == 0) gmax[0] = fmaxf(fmaxf(sm[0], sm[1]), fmaxf(sm[2], sm[3]));
}

// z[b][m] = sum_s qtb[b][m][s]   (qtb is B x M x S)
__global__ __launch_bounds__(256) void zsumt_kernel(const unsigned short* __restrict__ qtb,
                                                    float* __restrict__ z) {
  __shared__ float sred[4];
  const int b = blockIdx.x, m = blockIdx.y, tid = threadIdx.x;
  const unsigned short* p = qtb + ((long)b * cM + m) * cS + (long)tid * 16;
  bf16x8 a = *(const bf16x8*)p;
  bf16x8 c = *(const bf16x8*)(p + 8);
  float s = 0.f;
#pragma unroll
  for (int t = 0; t < 8; ++t) s += b2f((unsigned short)a[t]) + b2f((unsigned short)c[t]);
#pragma unroll
  for (int off = 32; off >= 1; off >>= 1) s += __shfl_down(s, off, 64);
  const int w = tid >> 6, lane = tid & 63;
  if (lane == 0) sred[w] = s;
  __syncthreads();
  if (tid == 0) z[b * cM + m] = sred[0] + sred[1] + sred[2] + sred[3];
}

// den[row] = dot(pq[row,:], z[b,:]); 4 rows/block
__global__ __launch_bounds__(256) void den_kernel(const unsigned short* __restrict__ P,
                                                  const float* __restrict__ z,
                                                  float* __restrict__ den) {
  const int w = threadIdx.x >> 6, lane = threadIdx.x & 63;
  const long row = (long)blockIdx.x * 4 + w;
  const float* zb = z + (row >> 12) * cM;
  const unsigned short* p = P + row * cM;
  float d = b2f(p[lane]) * zb[lane] + b2f(p[lane + 64]) * zb[lane + 64];
#pragma unroll
  for (int off = 32; off >= 1; off >>= 1) d += __shfl_down(d, off, 64);
  if (lane == 0) den[row] = d;
}

// layernorm in place (bf16 -> bf16), one row per block
__global__ __launch_bounds__(256) void ln_kernel(unsigned short* __restrict__ a,
                                                 const unsigned short* __restrict__ g,
                                                 const unsigned short* __restrict__ bb) {
  __shared__ float sred[8];
  const long row = blockIdx.x;
  unsigned short* ar = a + row * cE;
  const int tid = threadIdx.x;
  float v0 = b2f(ar[tid]), v1 = b2f(ar[tid + 256]);
  float s = v0 + v1, sq = v0 * v0 + v1 * v1;
#pragma unroll
  for (int off = 32; off >= 1; off >>= 1) {
    s  += __shfl_down(s, off, 64);
    sq += __shfl_down(sq, off, 64);
  }
  const int w = tid >> 6, lane = tid & 63;
  if (lane == 0) { sred[w] = s; sred[4 + w] = sq; }
  __syncthreads();
  const float st  = sred[0] + sred[1] + sred[2] + sred[3];
  const float sqt = sred[4] + sred[5] + sred[6] + sred[7];
  const float mean = st * (1.f / 512.f);
  const float var  = fmaxf(sqt * (1.f / 512.f) - mean * mean, 0.f);
  const float rstd = rsqrtf(var + 1e-5f);
  ar[tid]       = f2b((v0 - mean) * rstd * b2f(g[tid])       + b2f(bb[tid]));
  ar[tid + 256] = f2b((v1 - mean) * rstd * b2f(g[tid + 256]) + b2f(bb[tid + 256]));
}

// batched bf16 transpose: in (R x C) -> out (C x R); grid (C/32, R/32, batch)
__global__ __launch_bounds__(256) void transpose_kernel(const unsigned short* __restrict__ in,
                                                        unsigned short* __restrict__ out,
                                                        int R, int C, long sIn, long sOut) {
  __shared__ unsigned short t[32][33];
  in  += (long)blockIdx.z * sIn;
  out += (long)blockIdx.z * sOut;
  const int bx = blockIdx.x << 5, by = blockIdx.y << 5;
  const int tx = threadIdx.x & 31, ty = threadIdx.x >> 5;
#pragma unroll
  for (int i = ty; i < 32; i += 8) t[i][tx] = in[(long)(by + i) * C + bx + tx];
  __syncthreads();
#pragma unroll
  for (int i = ty; i < 32; i += 8) out[(long)(bx + i) * R + by + tx] = t[tx][i];
}

// final head: out[b] = relu(h[b,0,:]@Wr1+br1)@Wr2+br2 ; grid 16, block 256
__global__ __launch_bounds__(256) void head_kernel(const unsigned short* __restrict__ h,
                                                   const unsigned short* __restrict__ Wr1,
                                                   const unsigned short* __restrict__ br1,
                                                   const unsigned short* __restrict__ Wr2,
                                                   const unsigned short* __restrict__ br2,
                                                   void* __restrict__ out,
                                                   const int* __restrict__ flag) {
  __shared__ float pooled[cE];
  __shared__ float red[4];
  const int b = blockIdx.x, tid = threadIdx.x;
  pooled[tid]       = b2f(h[(long)b * cS * cE + tid]);
  pooled[tid + 256] = b2f(h[(long)b * cS * cE + tid + 256]);
  __syncthreads();
  float acc = b2f(br1[tid]);
  for (int e = 0; e < cE; ++e) acc += pooled[e] * b2f(Wr1[e * cHE + tid]);
  acc = fmaxf(acc, 0.f) * b2f(Wr2[tid]);
#pragma unroll
  for (int off = 32; off >= 1; off >>= 1) acc += __shfl_down(acc, off, 64);
  const int w = tid >> 6, lane = tid & 63;
  if (lane == 0) red[w] = acc;
  __syncthreads();
  if (tid == 0) {
    float r = red[0] + red[1] + red[2] + red[3] + b2f(br2[0]);
    if (flag[0]) ((float*)out)[b] = r;
    else         ((unsigned short*)out)[b] = f2b(r);
  }
}

// ---------------- host ----------------
extern "C" void kernel_launch(void* const* d_in, const int* in_sizes, int n_in,
                              void* d_out, int out_size, void* d_ws, size_t ws_size,
                              hipStream_t stream) {
  (void)in_sizes; (void)n_in; (void)out_size;

  char* ws = (char*)d_ws;
  size_t off = 0;
  auto alloc = [&](size_t bytes) -> void* {
    void* p = ws + off;
    off += (bytes + 255) & ~(size_t)255;
    return p;
  };
  // ---- memory plan (~236 MiB total) ----
  unsigned short* h   = (unsigned short*)alloc(cNBS * cE * 2);   // 67 MB residual (bf16)
  unsigned short* X   = (unsigned short*)alloc(cNBS * cE * 2);   // 67 MB: wstage -> q/k -> qtb -> att -> u1
  unsigned short* Y   = (unsigned short*)alloc(cNBS * cE * 2);   // 67 MB: xb/posb -> phik-tmp -> v^T -> a/y
  unsigned short* Pb  = (unsigned short*)alloc(cNBS * cM * 2);   // 16.8 MB phi(q)
  unsigned short* kvtb= (unsigned short*)alloc((long)cB * cE * cM * 2); // 2.1 MB
  float* vec64k       = (float*)alloc(cNBS * 4);                 // rnorm, then den
  float* z            = (float*)alloc(cB * cM * 4);
  float* partials     = (float*)alloc(512 * 4);
  float* gmaxf        = (float*)alloc(256);
  int*   dflag        = (int*)alloc(256);
  unsigned short* WiT = (unsigned short*)alloc((long)cE * cDIN * 2);
  unsigned short* WqT = (unsigned short*)alloc((long)cL * cE * cE * 2);
  unsigned short* WkT = (unsigned short*)alloc((long)cL * cE * cE * 2);
  unsigned short* WvT = (unsigned short*)alloc((long)cL * cE * cE * 2);
  unsigned short* WoT = (unsigned short*)alloc((long)cL * cE * cE * 2);
  unsigned short* RT  = (unsigned short*)alloc((long)cL * cM * cE * 2);
  unsigned short* W1T = (unsigned short*)alloc((long)cL * cFF * cE * 2);
  unsigned short* W2T = (unsigned short*)alloc((long)cL * cE * cFF * 2);
  unsigned short* sb  = (unsigned short*)alloc(160000 * 2);      // small converted tensors

  // staging of raw bf16 weights inside X (dead until first q GEMM)
  unsigned short* WqB = X;
  unsigned short* WkB = WqB + (long)cL * cE * cE;
  unsigned short* WvB = WkB + (long)cL * cE * cE;
  unsigned short* WoB = WvB + (long)cL * cE * cE;
  unsigned short* RmB = WoB + (long)cL * cE * cE;
  unsigned short* W1B = RmB + (long)cL * cE * cM;
  unsigned short* W2B = W1B + (long)cL * cE * cFF;
  unsigned short* WiB = W2B + (long)cL * cE * cFF;
  // staging of x, pos inside Y (dead until phi(k) tmp)
  unsigned short* xb   = Y;
  unsigned short* posb = Y + cNBS * cDIN;
  // small tensors inside sb
  unsigned short* biC  = sb;                 // 512
  unsigned short* bqC  = biC  + 512;         // 2048
  unsigned short* bkC  = bqC  + 2048;
  unsigned short* bvC  = bkC  + 2048;
  unsigned short* boC  = bvC  + 2048;
  unsigned short* b1C  = boC  + 2048;        // 8192
  unsigned short* b2C  = b1C  + 8192;        // 2048
  unsigned short* lngC = b2C  + 2048;        // 2048
  unsigned short* lnbC = lngC + 2048;        // 2048
  unsigned short* Wr1C = lnbC + 2048;        // 131072
  unsigned short* br1C = Wr1C + 131072;      // 256
  unsigned short* Wr2C = br1C + 256;         // 256
  unsigned short* br2C = Wr2C + 256;         // 1

  unsigned short* qtb  = X;   // pk^T (B x M x S) after k dead
  unsigned short* ytmp = Y;   // phi(k) row-major (B*S x M)
  unsigned short* vtb  = Y;   // v^T (B x E x S)
  unsigned short* attb = X;   // att output
  unsigned short* ab   = Y;   // a / y (LN in place)
  unsigned short* u1b  = X;   // FFN hidden chunk (8192 x 2048)

  if (off > ws_size) return;  // diagnostic fallback: fail absmax instead of faulting

  // ---- dtype detect + convert all inputs to bf16 ----
  detect_kernel<<<1, 64, 0, stream>>>((const unsigned short*)d_in[13], dflag);
  auto cvt = [&](const void* src, unsigned short* dst, long n) {
    cvt_kernel<<<(unsigned)((n + 255) / 256), 256, 0, stream>>>(src, dst, n, dflag);
  };
  cvt(d_in[0],  xb,   cNBS * cDIN);
  cvt(d_in[1],  WiB,  (long)cDIN * cE);
  cvt(d_in[2],  biC,  cE);
  cvt(d_in[3],  posb, (long)cS * cE);
  cvt(d_in[4],  WqB,  (long)cL * cE * cE);
  cvt(d_in[5],  bqC,  (long)cL * cE);
  cvt(d_in[6],  WkB,  (long)cL * cE * cE);
  cvt(d_in[7],  bkC,  (long)cL * cE);
  cvt(d_in[8],  WvB,  (long)cL * cE * cE);
  cvt(d_in[9],  bvC,  (long)cL * cE);
  cvt(d_in[10], WoB,  (long)cL * cE * cE);
  cvt(d_in[11], boC,  (long)cL * cE);
  cvt(d_in[12], RmB,  (long)cL * cE * cM);
  cvt(d_in[13], lngC, (long)cL * cE);
  cvt(d_in[14], lnbC, (long)cL * cE);
  cvt(d_in[15], W1B,  (long)cL * cE * cFF);
  cvt(d_in[16], b1C,  (long)cL * cFF);
  cvt(d_in[17], W2B,  (long)cL * cFF * cE);
  cvt(d_in[18], b2C,  (long)cL * cE);
  cvt(d_in[19], Wr1C, (long)cE * cHE);
  cvt(d_in[20], br1C, cHE);
  cvt(d_in[21], Wr2C, cHE);
  cvt(d_in[22], br2C, 1);

  typedef const unsigned short* cus;
  auto gemm = [&](const void* A, const void* Bt, const void* bias_, const void* Res_,
                  const float* aux_, float* pmax_, const float* gmx_, void* C,
                  long rows, int K, int N, float alpha, int flags,
                  long sA, long sB, long sC, int batches) {
    dim3 g((unsigned)(rows / 128), (unsigned)(N / 128), (unsigned)batches);
    gemm_kernel<<<g, dim3(256), 0, stream>>>(
        (const unsigned short*)A, (const unsigned short*)Bt,
        (const unsigned short*)bias_, (const unsigned short*)Res_,
        aux_, pmax_, gmx_, (unsigned short*)C, K, N, alpha, flags, sA, sB, sC);
  };

  // ---- weight pre-transposes (from bf16 staged copies) ----
  transpose_kernel<<<dim3(16, 2, 1), 256, 0, stream>>>(WiB, WiT, cDIN, cE, 0, 0);
  transpose_kernel<<<dim3(16, 16, cL), 256, 0, stream>>>(WqB, WqT, cE, cE, (long)cE * cE, (long)cE * cE);
  transpose_kernel<<<dim3(16, 16, cL), 256, 0, stream>>>(WkB, WkT, cE, cE, (long)cE * cE, (long)cE * cE);
  transpose_kernel<<<dim3(16, 16, cL), 256, 0, stream>>>(WvB, WvT, cE, cE, (long)cE * cE, (long)cE * cE);
  transpose_kernel<<<dim3(16, 16, cL), 256, 0, stream>>>(WoB, WoT, cE, cE, (long)cE * cE, (long)cE * cE);
  transpose_kernel<<<dim3(4, 16, cL), 256, 0, stream>>>(RmB, RT, cE, cM, (long)cE * cM, (long)cE * cM);
  transpose_kernel<<<dim3(64, 16, cL), 256, 0, stream>>>(W1B, W1T, cE, cFF, (long)cE * cFF, (long)cE * cFF);
  transpose_kernel<<<dim3(16, 64, cL), 256, 0, stream>>>(W2B, W2T, cFF, cE, (long)cFF * cE, (long)cFF * cE);

  // ---- input projection (bf16 h) + positional embedding ----
  gemm(xb, WiT, biC, nullptr, nullptr, nullptr, nullptr, h, cNBS, cDIN, cE, 1.f,
       FLAG_BIAS, 0, 0, 0, 1);
  addpos_kernel<<<16384, 256, 0, stream>>>(h, posb);

  const float scale      = 0.21022410381342863f;    // 512^-0.25
  const float halfscale2 = 0.022097086912079608f;   // 0.5 * 512^-0.5

  for (int i = 0; i < cL; ++i) {
    cus WqT_i = WqT + (long)i * cE * cE;  cus bq_i = bqC + (long)i * cE;
    cus WkT_i = WkT + (long)i * cE * cE;  cus bk_i = bkC + (long)i * cE;
    cus WvT_i = WvT + (long)i * cE * cE;  cus bv_i = bvC + (long)i * cE;
    cus WoT_i = WoT + (long)i * cE * cE;  cus bo_i = boC + (long)i * cE;
    cus RT_i  = RT  + (long)i * cM * cE;
    cus g_i   = lngC + (long)i * cE;      cus b_i  = lnbC + (long)i * cE;
    cus W1T_i = W1T + (long)i * cFF * cE; cus b1_i = b1C + (long)i * cFF;
    cus W2T_i = W2T + (long)i * cE * cFF; cus b2_i = b2C + (long)i * cE;

    // --- phi(q): q -> X; rownorm; two-pass max; Pb = phi(q) ---
    gemm(h, WqT_i, bq_i, nullptr, nullptr, nullptr, nullptr, X, cNBS, cE, cE, 1.f,
         FLAG_BIAS, 0, 0, 0, 1);
    rnorm_kernel<<<16384, 256, 0, stream>>>(X, vec64k, halfscale2);
    gemm(X, RT_i, nullptr, nullptr, vec64k, partials, nullptr, Pb, cNBS, cE, cM, scale,
         FLAG_PHI1, 0, 0, 0, 1);
    reducemax_kernel<<<1, 256, 0, stream>>>(partials, gmaxf, 512);
    gemm(X, RT_i, nullptr, nullptr, vec64k, nullptr, gmaxf, Pb, cNBS, cE, cM, scale,
         FLAG_PHI2, 0, 0, 0, 1);

    // --- phi(k): k -> X; phi(k) -> ytmp (Y); transpose -> qtb (X) ---
    gemm(h, WkT_i, bk_i, nullptr, nullptr, nullptr, nullptr, X, cNBS, cE, cE, 1.f,
         FLAG_BIAS, 0, 0, 0, 1);
    rnorm_kernel<<<16384, 256, 0, stream>>>(X, vec64k, halfscale2);
    gemm(X, RT_i, nullptr, nullptr, vec64k, partials, nullptr, ytmp, cNBS, cE, cM, scale,
         FLAG_PHI1, 0, 0, 0, 1);
    reducemax_kernel<<<1, 256, 0, stream>>>(partials, gmaxf, 512);
    gemm(X, RT_i, nullptr, nullptr, vec64k, nullptr, gmaxf, ytmp, cNBS, cE, cM, scale,
         FLAG_PHI2, 0, 0, 0, 1);
    transpose_kernel<<<dim3(4, 128, cB), 256, 0, stream>>>(ytmp, qtb, cS, cM,
                                                           (long)cS * cM, (long)cS * cM);

    // --- v projection stored directly transposed: vtb (Y) = v^T (B x E x S) ---
    gemm(h, WvT_i, bv_i, nullptr, nullptr, nullptr, nullptr, vtb, cNBS, cE, cE, 1.f,
         FLAG_BIAS | FLAG_VT, 0, 0, 0, 1);

    // --- z, den ---
    zsumt_kernel<<<dim3(cB, cM), 256, 0, stream>>>(qtb, z);
    den_kernel<<<16384, 256, 0, stream>>>(Pb, z, vec64k);

    // --- kv^T[b] (E x M) = v^T[b] (E x S) @ pk[b] (S x M) ---
    gemm(vtb, qtb, nullptr, nullptr, nullptr, nullptr, nullptr, kvtb, cE, cS, cM, 1.f,
         0, (long)cE * cS, (long)cM * cS, (long)cE * cM, cB);
    // --- att[b] (S x E) = (pq[b] @ kv[b]) / (den+1e-6) -> X ---
    gemm(Pb, kvtb, nullptr, nullptr, vec64k, nullptr, nullptr, attb, cS, cM, cE, 1.f,
         FLAG_DEN, (long)cS * cM, (long)cE * cM, (long)cS * cE, cB);

    // --- a = att @ Wo + bo -> Y ; LN in place ---
    gemm(attb, WoT_i, bo_i, nullptr, nullptr, nullptr, nullptr, ab, cNBS, cE, cE, 1.f,
         FLAG_BIAS, 0, 0, 0, 1);
    ln_kernel<<<cNBS, 256, 0, stream>>>(ab, g_i, b_i);

    // --- FFN in 8 row-chunks of 8192; h += ffn(y) ---
    for (int c = 0; c < 8; ++c) {
      const unsigned short* yc = ab + (long)c * 8192 * cE;
      unsigned short* hc = h + (long)c * 8192 * cE;
      gemm(yc, W1T_i, b1_i, nullptr, nullptr, nullptr, nullptr, u1b, 8192, cE, cFF, 1.f,
           FLAG_BIAS | FLAG_GELU, 0, 0, 0, 1);
      gemm(u1b, W2T_i, b2_i, hc, nullptr, nullptr, nullptr, hc, 8192, cFF, cE, 1.f,
           FLAG_BIAS | FLAG_RES, 0, 0, 0, 1);
    }
  }

  head_kernel<<<cB, 256, 0, stream>>>(h, Wr1C, br1C, Wr2C, br2C, d_out, dflag);
}

// Round 10
// 4447.301 us; speedup vs baseline: 1.3417x; 1.2958x over previous
//
#include <hip/hip_runtime.h>
#include <math.h>

// ---------------- problem constants ----------------
static constexpr int  cB   = 16;
static constexpr int  cS   = 4096;
static constexpr int  cDIN = 64;
static constexpr int  cE   = 512;
static constexpr int  cM   = 128;
static constexpr int  cL   = 4;
static constexpr int  cFF  = 2048;   // 4*E
static constexpr int  cHE  = 256;    // E/2
static constexpr long cNBS = (long)cB * cS;   // 65536 rows

typedef __attribute__((ext_vector_type(8))) short  bf16x8;
typedef __attribute__((ext_vector_type(4))) short  bf16x4;
typedef __attribute__((ext_vector_type(4))) float  f32x4;

typedef const __attribute__((address_space(1))) unsigned int g_u32;
typedef __attribute__((address_space(3))) unsigned int l_u32;

__device__ __forceinline__ float b2f(unsigned short u) {
  union { unsigned int i; float f; } x; x.i = ((unsigned int)u) << 16; return x.f;
}
__device__ __forceinline__ unsigned short f2b(float f) {
  union { float f; unsigned int i; } x; x.f = f;
  unsigned int r = x.i + 0x7FFFu + ((x.i >> 16) & 1u);   // RNE
  return (unsigned short)(r >> 16);
}

// ---------------- GEMM: C[rows x N] = f(alpha*A@Bt^T + bias) -------------
// A: rows x K bf16 (row stride lda). Bt: N x K bf16 (row stride ldb).
#define FLAG_BIAS    2
#define FLAG_GELU    4
#define FLAG_RES     8     // += bf16 Res[idx]
#define FLAG_VT      16    // store transposed per 4096-row batch (E x S), LDS-staged
#define FLAG_DEN     32    // *= 1/(aux[zb*rowsPerBatch+rr]+1e-6)
#define FLAG_PHIK    128   // phi logit pass: f32 (acc*alpha - hs2*||row||^2) + block max
#define FLAG_F32OUT  256   // store f32 (split-K partials)
#define FLAG_SPLITK8 512   // blockIdx.z = batch*8 + k-chunk; C indexed by blockIdx.z

#define GMT 128
#define GNT 128
#define GBK 32

__global__ __launch_bounds__(256, 2)
void gemm_kernel(const unsigned short* __restrict__ A,
                 const unsigned short* __restrict__ Bt,
                 const unsigned short* __restrict__ bias,
                 const unsigned short* __restrict__ Res,
                 const float* __restrict__ aux,
                 float* __restrict__ pmax,
                 void* __restrict__ C,
                 int K, int N, int lda, int ldb, float alpha, int flags,
                 long sA, long sB, long sC)
{
  // 18 KB shared: As(8K)+Bs(8K) during K-loop; stage aliases them post-loop (VT).
  __shared__ __align__(16) unsigned char sraw[18048];
  unsigned short (*As)[32] = (unsigned short (*)[32])sraw;
  unsigned short (*Bs)[32] = (unsigned short (*)[32])(sraw + 8192);
  unsigned short (*stage)[136] = (unsigned short (*)[136])sraw;   // VT post-loop (17408 B)
  float* wred  = (float*)(sraw + 17472);                          // PHIK (16 B)
  float* ssrow = (float*)(sraw + 16384);                          // PHIK (512 B)

  const int tid  = threadIdx.x;
  const int lane = tid & 63;
  const int wid  = tid >> 6;
  long zb = blockIdx.z;            // batch index (for A/B/aux)
  const long zc = blockIdx.z;      // C-store base index (keeps k-chunk for split-K)
  int koff = 0;
  if (flags & FLAG_SPLITK8) { koff = (int)(zb & 7) * K; zb >>= 3; }

  const unsigned short* Ab = A + zb * sA + (long)blockIdx.x * GMT * lda + koff;
  const unsigned short* Bb = Bt + zb * sB + (long)blockIdx.y * GNT * ldb + koff;

  // async staging: lane's LDS dest = tile_base + wid*1024 + lane*16 (contiguous)
  const int srow = wid * 16 + (lane >> 2);   // 0..63
  const int scol = (lane & 3) << 3;          // 0,8,16,24
  const unsigned short* gA = Ab + (long)srow * lda + scol;
  const unsigned short* gB = Bb + (long)srow * ldb + scol;
  l_u32* lA0 = (l_u32*)&As[srow][scol];
  l_u32* lA1 = (l_u32*)&As[srow + 64][scol];
  l_u32* lB0 = (l_u32*)&Bs[srow][scol];
  l_u32* lB1 = (l_u32*)&Bs[srow + 64][scol];

  const f32x4 fzero = {0.f, 0.f, 0.f, 0.f};
  f32x4 acc[4][4];
#pragma unroll
  for (int i = 0; i < 4; ++i)
#pragma unroll
    for (int j = 0; j < 4; ++j) acc[i][j] = fzero;

  const int wm = (wid >> 1) << 6;
  const int wn = (wid & 1) << 6;
  const int fm = lane & 15;
  const int kq = (lane >> 4) << 3;
  const bool doSS = (flags & FLAG_PHIK) != 0;
  float ss[4] = {0.f, 0.f, 0.f, 0.f};

  const long ka64 = (long)64 * lda, kb64 = (long)64 * ldb;
  for (int k0 = 0; k0 < K; k0 += GBK) {
    __builtin_amdgcn_global_load_lds((g_u32*)(gA + k0),        lA0, 16, 0, 0);
    __builtin_amdgcn_global_load_lds((g_u32*)(gA + ka64 + k0), lA1, 16, 0, 0);
    __builtin_amdgcn_global_load_lds((g_u32*)(gB + k0),        lB0, 16, 0, 0);
    __builtin_amdgcn_global_load_lds((g_u32*)(gB + kb64 + k0), lB1, 16, 0, 0);
    __syncthreads();

    bf16x8 af[4], bfv[4];
#pragma unroll
    for (int i = 0; i < 4; ++i) {
      af[i]  = *(const bf16x8*)&As[wm + i * 16 + fm][kq];
      bfv[i] = *(const bf16x8*)&Bs[wn + i * 16 + fm][kq];
    }
    if (doSS) {
#pragma unroll
      for (int i = 0; i < 4; ++i)
#pragma unroll
        for (int t = 0; t < 8; ++t) {
          float a = b2f((unsigned short)af[i][t]); ss[i] += a * a;
        }
    }
#pragma unroll
    for (int i = 0; i < 4; ++i)
#pragma unroll
      for (int j = 0; j < 4; ++j)
        acc[i][j] = __builtin_amdgcn_mfma_f32_16x16x32_bf16(af[i], bfv[j], acc[i][j], 0, 0, 0);
    __syncthreads();
  }

  // epilogue: C/D layout col=lane&15, row=(lane>>4)*4+reg  [verified m89/m91]
  const int rq = (lane >> 4) << 2;
  const long crow0 = (long)blockIdx.x * GMT + wm;
  const int  ccol0 = blockIdx.y * GNT + wn;

  if (flags & FLAG_PHIK) {
    // faithful phi logits: l = alpha*(x@R) - hs2*||x_row||^2, f32 out + block max
#pragma unroll
    for (int i = 0; i < 4; ++i) {
      float s = ss[i];
      s += __shfl_down(s, 16, 64);
      s += __shfl_down(s, 32, 64);
      if (lane < 16) ssrow[wm + i * 16 + lane] = s;
    }
    __syncthreads();
    float* Cf = (float*)C;
    float mx = -3.0e38f;
#pragma unroll
    for (int j = 0; j < 4; ++j) {
      const int cc = ccol0 + j * 16 + fm;
#pragma unroll
      for (int i = 0; i < 4; ++i)
#pragma unroll
        for (int r = 0; r < 4; ++r) {
          const int rloc = wm + i * 16 + rq + r;
          const long rr = crow0 + i * 16 + rq + r;
          float l = acc[i][j][r] * alpha - 0.022097086912079608f * ssrow[rloc];
          mx = fmaxf(mx, l);
          Cf[rr * (long)N + cc] = l;
        }
    }
#pragma unroll
    for (int off = 32; off >= 1; off >>= 1) mx = fmaxf(mx, __shfl_down(mx, off, 64));
    if (lane == 0) wred[wid] = mx;
    __syncthreads();
    if (tid == 0)
      pmax[blockIdx.x] = fmaxf(fmaxf(wred[0], wred[1]), fmaxf(wred[2], wred[3]));
    return;
  }

  if (flags & FLAG_VT) {
    // stage 64 cols x 128 rows in LDS, then coalesced column stores (64B/thread)
    unsigned short* Cb = (unsigned short*)C;
    const int bb = (blockIdx.x * GMT) >> 12;
    const long sbase = (long)((blockIdx.x * GMT) & (cS - 1));
#pragma unroll
    for (int rnd = 0; rnd < 2; ++rnd) {
      if ((wn >> 6) == rnd) {
#pragma unroll
        for (int j = 0; j < 4; ++j) {
          const int cc = ccol0 + j * 16 + fm;
          const float bv = (flags & FLAG_BIAS) ? b2f(bias[cc]) : 0.f;
          const int cl = j * 16 + fm;
#pragma unroll
          for (int i = 0; i < 4; ++i)
#pragma unroll
            for (int r = 0; r < 4; ++r)
              stage[cl][wm + i * 16 + rq + r] = f2b(acc[i][j][r] * alpha + bv);
        }
      }
      __syncthreads();
      {
        const int cl = tid >> 2;
        const int sseg = (tid & 3) << 5;
        const int gcol = blockIdx.y * GNT + rnd * 64 + cl;
        unsigned short* dst = Cb + (long)bb * cE * cS + (long)gcol * cS + sbase + sseg;
#pragma unroll
        for (int t = 0; t < 4; ++t)
          *(bf16x8*)(dst + t * 8) = *(const bf16x8*)&stage[cl][sseg + t * 8];
      }
      __syncthreads();
    }
    return;
  }

  // generic epilogue (C indexed by zc so split-K chunks land in distinct slabs)
  const long rowsPerBatch = (long)gridDim.x * GMT;
#pragma unroll
  for (int j = 0; j < 4; ++j) {
    const int cc = ccol0 + j * 16 + fm;
    const float bv = (flags & FLAG_BIAS) ? b2f(bias[cc]) : 0.f;
#pragma unroll
    for (int i = 0; i < 4; ++i) {
      const long rbase = crow0 + i * 16 + rq;
#pragma unroll
      for (int r = 0; r < 4; ++r) {
        const long rr = rbase + r;
        float v = acc[i][j][r] * alpha + bv;
        if (flags & FLAG_GELU) v = 0.5f * v * (1.f + erff(v * 0.7071067811865475f));
        if (flags & FLAG_DEN)
          v *= 1.f / (fmaxf(aux[zb * rowsPerBatch + rr], 0.f) + 1e-6f);
        const long idx = zc * sC + rr * (long)N + cc;
        if (flags & FLAG_RES) v += b2f(Res[idx]);
        if (flags & FLAG_F32OUT) ((float*)C)[idx] = v;
        else                     ((unsigned short*)C)[idx] = f2b(v);
      }
    }
  }
}

// ---------------- dtype shim ----------------
__global__ void detect_kernel(const unsigned short* __restrict__ lng,
                              int* __restrict__ flag) {
  if (threadIdx.x == 0 && blockIdx.x == 0) flag[0] = (lng[0] == 0) ? 1 : 0;
}

__global__ __launch_bounds__(256) void cvt_kernel(const void* __restrict__ in,
                                                  unsigned short* __restrict__ out,
                                                  long n, const int* __restrict__ flag) {
  long i = (long)blockIdx.x * 256 + threadIdx.x;
  if (i >= n) return;
  if (flag[0]) out[i] = f2b(((const float*)in)[i]);
  else         out[i] = ((const unsigned short*)in)[i];
}

// ---------------- small kernels ----------------
__global__ __launch_bounds__(256) void addpos_kernel(unsigned short* __restrict__ h,
                                                     const unsigned short* __restrict__ pos) {
  long i = ((long)blockIdx.x * 256 + threadIdx.x) * 8;
  long se = i % ((long)cS * cE);
  bf16x8 v = *(bf16x8*)&h[i];
  bf16x8 p = *(const bf16x8*)&pos[se];
#pragma unroll
  for (int r = 0; r < 8; ++r)
    v[r] = (short)f2b(b2f((unsigned short)v[r]) + b2f((unsigned short)p[r]));
  *(bf16x8*)&h[i] = v;
}

// gmax[0] = max(partials[0..n)); single block
__global__ __launch_bounds__(256) void reducemax_kernel(const float* __restrict__ partials,
                                                        float* __restrict__ gmax, int n) {
  __shared__ float sm[4];
  float mx = -3.0e38f;
  for (int i = threadIdx.x; i < n; i += 256) mx = fmaxf(mx, partials[i]);
#pragma unroll
  for (int off = 32; off >= 1; off >>= 1) mx = fmaxf(mx, __shfl_down(mx, off, 64));
  const int w = threadIdx.x >> 6, lane = threadIdx.x & 63;
  if (lane == 0) sm[w] = mx;
  __syncthreads();
  if (threadIdx.x == 0) gmax[0] = fmaxf(fmaxf(sm[0], sm[1]), fmaxf(sm[2], sm[3]));
}

// elementwise exp (row-major): P = bf16(exp(lf - gm)/sqrt(M))
__global__ __launch_bounds__(256) void expq_kernel(const float* __restrict__ lf,
                                                   const float* __restrict__ gmx,
                                                   unsigned short* __restrict__ P) {
  long i = ((long)blockIdx.x * 256 + threadIdx.x) * 4;
  const float gm = gmx[0];
  f32x4 v = *(const f32x4*)&lf[i];
  bf16x4 o;
#pragma unroll
  for (int r = 0; r < 4; ++r)
    o[r] = (short)f2b(__expf(fminf(v[r] - gm, 0.f)) * 0.08838834764831845f);
  *(bf16x4*)&P[i] = o;
}

// fused exp + transpose: lf (B x S x M f32 logits) -> out (B x M x S bf16 phi)
__global__ __launch_bounds__(256) void expT_kernel(const float* __restrict__ lf,
                                                   const float* __restrict__ gmx,
                                                   unsigned short* __restrict__ out) {
  __shared__ unsigned short t[32][33];
  const int b = blockIdx.z;
  const float gm = gmx[0];
  const int bx = blockIdx.x << 5, by = blockIdx.y << 5;   // bx: M, by: S
  const int tx = threadIdx.x & 31, ty = threadIdx.x >> 5;
  const float* src = lf + (long)b * cS * cM;
  unsigned short* dst = out + (long)b * cM * cS;
#pragma unroll
  for (int i = ty; i < 32; i += 8) {
    float l = src[(long)(by + i) * cM + bx + tx];
    t[i][tx] = f2b(__expf(fminf(l - gm, 0.f)) * 0.08838834764831845f);
  }
  __syncthreads();
#pragma unroll
  for (int i = ty; i < 32; i += 8)
    dst[(long)(bx + i) * cS + by + tx] = t[tx][i];
}

// reduce 8 split-K partials: kvtb[o] = bf16( sum_sc kvp[(b*8+sc)*65536 + r] )
__global__ __launch_bounds__(256) void kvred_kernel(const float* __restrict__ kvp,
                                                    unsigned short* __restrict__ kvtb) {
  const long o = (long)blockIdx.x * 256 + threadIdx.x;   // < 16*65536
  const long b = o >> 16;
  const long r = o & 65535;
  const float* p = kvp + (b << 19) + r;
  float s = 0.f;
#pragma unroll
  for (int sc = 0; sc < 8; ++sc) s += p[(long)sc << 16];
  kvtb[o] = f2b(s);
}

// z[b][m] = sum_s qtb[b][m][s]   (qtb is B x M x S)
__global__ __launch_bounds__(256) void zsumt_kernel(const unsigned short* __restrict__ qtb,
                                                    float* __restrict__ z) {
  __shared__ float sred[4];
  const int b = blockIdx.x, m = blockIdx.y, tid = threadIdx.x;
  const unsigned short* p = qtb + ((long)b * cM + m) * cS + (long)tid * 16;
  bf16x8 a = *(const bf16x8*)p;
  bf16x8 c = *(const bf16x8*)(p + 8);
  float s = 0.f;
#pragma unroll
  for (int t = 0; t < 8; ++t) s += b2f((unsigned short)a[t]) + b2f((unsigned short)c[t]);
#pragma unroll
  for (int off = 32; off >= 1; off >>= 1) s += __shfl_down(s, off, 64);
  const int w = tid >> 6, lane = tid & 63;
  if (lane == 0) sred[w] = s;
  __syncthreads();
  if (tid == 0) z[b * cM + m] = sred[0] + sred[1] + sred[2] + sred[3];
}

// den[row] = dot(pq[row,:], z[b,:]); 4 rows/block
__global__ __launch_bounds__(256) void den_kernel(const unsigned short* __restrict__ P,
                                                  const float* __restrict__ z,
                                                  float* __restrict__ den) {
  const int w = threadIdx.x >> 6, lane = threadIdx.x & 63;
  const long row = (long)blockIdx.x * 4 + w;
  const float* zb = z + (row >> 12) * cM;
  const unsigned short* p = P + row * cM;
  float d = b2f(p[lane]) * zb[lane] + b2f(p[lane + 64]) * zb[lane + 64];
#pragma unroll
  for (int off = 32; off >= 1; off >>= 1) d += __shfl_down(d, off, 64);
  if (lane == 0) den[row] = d;
}

// layernorm in place (bf16 -> bf16), one row per block
__global__ __launch_bounds__(256) void ln_kernel(unsigned short* __restrict__ a,
                                                 const unsigned short* __restrict__ g,
                                                 const unsigned short* __restrict__ bb) {
  __shared__ float sred[8];
  const long row = blockIdx.x;
  unsigned short* ar = a + row * cE;
  const int tid = threadIdx.x;
  float v0 = b2f(ar[tid]), v1 = b2f(ar[tid + 256]);
  float s = v0 + v1, sq = v0 * v0 + v1 * v1;
#pragma unroll
  for (int off = 32; off >= 1; off >>= 1) {
    s  += __shfl_down(s, off, 64);
    sq += __shfl_down(sq, off, 64);
  }
  const int w = tid >> 6, lane = tid & 63;
  if (lane == 0) { sred[w] = s; sred[4 + w] = sq; }
  __syncthreads();
  const float st  = sred[0] + sred[1] + sred[2] + sred[3];
  const float sqt = sred[4] + sred[5] + sred[6] + sred[7];
  const float mean = st * (1.f / 512.f);
  const float var  = fmaxf(sqt * (1.f / 512.f) - mean * mean, 0.f);
  const float rstd = rsqrtf(var + 1e-5f);
  ar[tid]       = f2b((v0 - mean) * rstd * b2f(g[tid])       + b2f(bb[tid]));
  ar[tid + 256] = f2b((v1 - mean) * rstd * b2f(g[tid + 256]) + b2f(bb[tid + 256]));
}

// batched bf16 transpose: in (R x C) -> out (C x R); grid (C/32, R/32, batch)
__global__ __launch_bounds__(256) void transpose_kernel(const unsigned short* __restrict__ in,
                                                        unsigned short* __restrict__ out,
                                                        int R, int C, long sIn, long sOut) {
  __shared__ unsigned short t[32][33];
  in  += (long)blockIdx.z * sIn;
  out += (long)blockIdx.z * sOut;
  const int bx = blockIdx.x << 5, by = blockIdx.y << 5;
  const int tx = threadIdx.x & 31, ty = threadIdx.x >> 5;
#pragma unroll
  for (int i = ty; i < 32; i += 8) t[i][tx] = in[(long)(by + i) * C + bx + tx];
  __syncthreads();
#pragma unroll
  for (int i = ty; i < 32; i += 8) out[(long)(bx + i) * R + by + tx] = t[tx][i];
}

// final head
__global__ __launch_bounds__(256) void head_kernel(const unsigned short* __restrict__ h,
                                                   const unsigned short* __restrict__ Wr1,
                                                   const unsigned short* __restrict__ br1,
                                                   const unsigned short* __restrict__ Wr2,
                                                   const unsigned short* __restrict__ br2,
                                                   void* __restrict__ out,
                                                   const int* __restrict__ flag) {
  __shared__ float pooled[cE];
  __shared__ float red[4];
  const int b = blockIdx.x, tid = threadIdx.x;
  pooled[tid]       = b2f(h[(long)b * cS * cE + tid]);
  pooled[tid + 256] = b2f(h[(long)b * cS * cE + tid + 256]);
  __syncthreads();
  float acc = b2f(br1[tid]);
  for (int e = 0; e < cE; ++e) acc += pooled[e] * b2f(Wr1[e * cHE + tid]);
  acc = fmaxf(acc, 0.f) * b2f(Wr2[tid]);
#pragma unroll
  for (int off = 32; off >= 1; off >>= 1) acc += __shfl_down(acc, off, 64);
  const int w = tid >> 6, lane = tid & 63;
  if (lane == 0) red[w] = acc;
  __syncthreads();
  if (tid == 0) {
    float r = red[0] + red[1] + red[2] + red[3] + b2f(br2[0]);
    if (flag[0]) ((float*)out)[b] = r;
    else         ((unsigned short*)out)[b] = f2b(r);
  }
}

// ---------------- host ----------------
extern "C" void kernel_launch(void* const* d_in, const int* in_sizes, int n_in,
                              void* d_out, int out_size, void* d_ws, size_t ws_size,
                              hipStream_t stream) {
  (void)in_sizes; (void)n_in; (void)out_size;

  char* ws = (char*)d_ws;
  size_t off = 0;
  auto alloc = [&](size_t bytes) -> void* {
    void* p = ws + off;
    off += (bytes + 255) & ~(size_t)255;
    return p;
  };
  // ---- memory plan (~236 MiB total) ----
  unsigned short* h   = (unsigned short*)alloc(cNBS * cE * 2);   // 67 MB residual
  unsigned short* X   = (unsigned short*)alloc(cNBS * cE * 2);   // 67 MB multi-use
  unsigned short* Y   = (unsigned short*)alloc(cNBS * cE * 2);   // 67 MB multi-use
  unsigned short* Pb  = (unsigned short*)alloc(cNBS * cM * 2);   // 16.8 MB phi(q)
  unsigned short* kvtb= (unsigned short*)alloc((long)cB * cE * cM * 2); // 2.1 MB
  float* vec64k       = (float*)alloc(cNBS * 4);                 // den
  float* z            = (float*)alloc(cB * cM * 4);
  float* partials     = (float*)alloc(512 * 4);
  float* gmaxf        = (float*)alloc(256);
  int*   dflag        = (int*)alloc(256);
  unsigned short* WiT = (unsigned short*)alloc((long)cE * cDIN * 2);
  unsigned short* WqT = (unsigned short*)alloc((long)cL * cE * cE * 2);
  unsigned short* WkT = (unsigned short*)alloc((long)cL * cE * cE * 2);
  unsigned short* WvT = (unsigned short*)alloc((long)cL * cE * cE * 2);
  unsigned short* WoT = (unsigned short*)alloc((long)cL * cE * cE * 2);
  unsigned short* RT  = (unsigned short*)alloc((long)cL * cM * cE * 2);
  unsigned short* W1T = (unsigned short*)alloc((long)cL * cFF * cE * 2);
  unsigned short* W2T = (unsigned short*)alloc((long)cL * cE * cFF * 2);
  unsigned short* sb  = (unsigned short*)alloc(160000 * 2);

  // weight staging inside X (dead until first q GEMM)
  unsigned short* WqB = X;
  unsigned short* WkB = WqB + (long)cL * cE * cE;
  unsigned short* WvB = WkB + (long)cL * cE * cE;
  unsigned short* WoB = WvB + (long)cL * cE * cE;
  unsigned short* RmB = WoB + (long)cL * cE * cE;
  unsigned short* W1B = RmB + (long)cL * cE * cM;
  unsigned short* W2B = W1B + (long)cL * cE * cFF;
  unsigned short* WiB = W2B + (long)cL * cE * cFF;
  // x, pos staging inside Y
  unsigned short* xb   = Y;
  unsigned short* posb = Y + cNBS * cDIN;
  // small tensors inside sb
  unsigned short* biC  = sb;
  unsigned short* bqC  = biC  + 512;
  unsigned short* bkC  = bqC  + 2048;
  unsigned short* bvC  = bkC  + 2048;
  unsigned short* boC  = bvC  + 2048;
  unsigned short* b1C  = boC  + 2048;
  unsigned short* b2C  = b1C  + 8192;
  unsigned short* lngC = b2C  + 2048;
  unsigned short* lnbC = lngC + 2048;
  unsigned short* Wr1C = lnbC + 2048;
  unsigned short* br1C = Wr1C + 131072;
  unsigned short* Wr2C = br1C + 256;
  unsigned short* br2C = Wr2C + 256;

  unsigned short* qtb  = X;                       // pk^T (B x M x S), 16.8 MB
  float* kvp           = (float*)(X + cNBS * cM); // split-K partials, 33.5 MB
  float* logf          = (float*)Y;               // phi logits f32, 33.5 MB (q then k)
  unsigned short* vtb  = Y;                       // v^T (B x E x S)
  unsigned short* attb = X;                       // att output
  unsigned short* ab   = Y;                       // a / y (LN in place)
  unsigned short* u1b  = X;                       // FFN hidden chunk (16384 x 2048)

  if (off > ws_size) return;

  // ---- dtype detect + convert all inputs to bf16 ----
  detect_kernel<<<1, 64, 0, stream>>>((const unsigned short*)d_in[13], dflag);
  auto cvt = [&](const void* src, unsigned short* dst, long n) {
    cvt_kernel<<<(unsigned)((n + 255) / 256), 256, 0, stream>>>(src, dst, n, dflag);
  };
  cvt(d_in[0],  xb,   cNBS * cDIN);
  cvt(d_in[1],  WiB,  (long)cDIN * cE);
  cvt(d_in[2],  biC,  cE);
  cvt(d_in[3],  posb, (long)cS * cE);
  cvt(d_in[4],  WqB,  (long)cL * cE * cE);
  cvt(d_in[5],  bqC,  (long)cL * cE);
  cvt(d_in[6],  WkB,  (long)cL * cE * cE);
  cvt(d_in[7],  bkC,  (long)cL * cE);
  cvt(d_in[8],  WvB,  (long)cL * cE * cE);
  cvt(d_in[9],  bvC,  (long)cL * cE);
  cvt(d_in[10], WoB,  (long)cL * cE * cE);
  cvt(d_in[11], boC,  (long)cL * cE);
  cvt(d_in[12], RmB,  (long)cL * cE * cM);
  cvt(d_in[13], lngC, (long)cL * cE);
  cvt(d_in[14], lnbC, (long)cL * cE);
  cvt(d_in[15], W1B,  (long)cL * cE * cFF);
  cvt(d_in[16], b1C,  (long)cL * cFF);
  cvt(d_in[17], W2B,  (long)cL * cFF * cE);
  cvt(d_in[18], b2C,  (long)cL * cE);
  cvt(d_in[19], Wr1C, (long)cE * cHE);
  cvt(d_in[20], br1C, cHE);
  cvt(d_in[21], Wr2C, cHE);
  cvt(d_in[22], br2C, 1);

  typedef const unsigned short* cus;
  auto gemm = [&](const void* A, const void* Bt, const void* bias_,
                  const float* aux_, float* pmax_, void* C,
                  long rows, int K, int N, int lda, int ldb, float alpha, int flags,
                  long sA, long sB, long sC, int batches, const void* Res_ = nullptr) {
    dim3 g((unsigned)(rows / 128), (unsigned)(N / 128), (unsigned)batches);
    gemm_kernel<<<g, dim3(256), 0, stream>>>(
        (const unsigned short*)A, (const unsigned short*)Bt,
        (const unsigned short*)bias_, (const unsigned short*)Res_,
        aux_, pmax_, C, K, N, lda, ldb, alpha, flags, sA, sB, sC);
  };

  // ---- weight pre-transposes ----
  transpose_kernel<<<dim3(16, 2, 1), 256, 0, stream>>>(WiB, WiT, cDIN, cE, 0, 0);
  transpose_kernel<<<dim3(16, 16, cL), 256, 0, stream>>>(WqB, WqT, cE, cE, (long)cE * cE, (long)cE * cE);
  transpose_kernel<<<dim3(16, 16, cL), 256, 0, stream>>>(WkB, WkT, cE, cE, (long)cE * cE, (long)cE * cE);
  transpose_kernel<<<dim3(16, 16, cL), 256, 0, stream>>>(WvB, WvT, cE, cE, (long)cE * cE, (long)cE * cE);
  transpose_kernel<<<dim3(16, 16, cL), 256, 0, stream>>>(WoB, WoT, cE, cE, (long)cE * cE, (long)cE * cE);
  transpose_kernel<<<dim3(4, 16, cL), 256, 0, stream>>>(RmB, RT, cE, cM, (long)cE * cM, (long)cE * cM);
  transpose_kernel<<<dim3(64, 16, cL), 256, 0, stream>>>(W1B, W1T, cE, cFF, (long)cE * cFF, (long)cE * cFF);
  transpose_kernel<<<dim3(16, 64, cL), 256, 0, stream>>>(W2B, W2T, cFF, cE, (long)cFF * cE, (long)cFF * cE);

  // ---- input projection + positional embedding ----
  gemm(xb, WiT, biC, nullptr, nullptr, h, cNBS, cDIN, cE, cDIN, cDIN, 1.f,
       FLAG_BIAS, 0, 0, 0, 1);
  addpos_kernel<<<16384, 256, 0, stream>>>(h, posb);

  const float scale = 0.21022410381342863f;    // 512^-0.25

  for (int i = 0; i < cL; ++i) {
    cus WqT_i = WqT + (long)i * cE * cE;  cus bq_i = bqC + (long)i * cE;
    cus WkT_i = WkT + (long)i * cE * cE;  cus bk_i = bkC + (long)i * cE;
    cus WvT_i = WvT + (long)i * cE * cE;  cus bv_i = bvC + (long)i * cE;
    cus WoT_i = WoT + (long)i * cE * cE;  cus bo_i = boC + (long)i * cE;
    cus RT_i  = RT  + (long)i * cM * cE;
    cus g_i   = lngC + (long)i * cE;      cus b_i  = lnbC + (long)i * cE;
    cus W1T_i = W1T + (long)i * cFF * cE; cus b1_i = b1C + (long)i * cFF;
    cus W2T_i = W2T + (long)i * cE * cFF; cus b2_i = b2C + (long)i * cE;

    // --- phi(q): q -> X; faithful logits (rownorm fused) -> Y f32 + global max;
    //     exp (row-major) -> Pb ---
    gemm(h, WqT_i, bq_i, nullptr, nullptr, X, cNBS, cE, cE, cE, cE, 1.f,
         FLAG_BIAS, 0, 0, 0, 1);
    gemm(X, RT_i, nullptr, nullptr, partials, logf, cNBS, cE, cM, cE, cE, scale,
         FLAG_PHIK, 0, 0, 0, 1);
    reducemax_kernel<<<1, 256, 0, stream>>>(partials, gmaxf, 512);
    expq_kernel<<<8192, 256, 0, stream>>>(logf, gmaxf, Pb);

    // --- phi(k): k -> X; logits -> Y f32 + global max; exp+transpose -> qtb ---
    gemm(h, WkT_i, bk_i, nullptr, nullptr, X, cNBS, cE, cE, cE, cE, 1.f,
         FLAG_BIAS, 0, 0, 0, 1);
    gemm(X, RT_i, nullptr, nullptr, partials, logf, cNBS, cE, cM, cE, cE, scale,
         FLAG_PHIK, 0, 0, 0, 1);
    reducemax_kernel<<<1, 256, 0, stream>>>(partials, gmaxf, 512);
    expT_kernel<<<dim3(4, 128, cB), 256, 0, stream>>>(logf, gmaxf, qtb);

    // --- v projection, stored transposed via LDS-staged epilogue ---
    gemm(h, WvT_i, bv_i, nullptr, nullptr, vtb, cNBS, cE, cE, cE, cE, 1.f,
         FLAG_BIAS | FLAG_VT, 0, 0, 0, 1);

    // --- z, den ---
    zsumt_kernel<<<dim3(cB, cM), 256, 0, stream>>>(qtb, z);
    den_kernel<<<16384, 256, 0, stream>>>(Pb, z, vec64k);

    // --- kv^T[b] = v^T[b] @ pk[b], split-K x8 (f32 partials) + reduce ---
    gemm(vtb, qtb, nullptr, nullptr, nullptr, kvp, cE, cS / 8, cM, cS, cS, 1.f,
         FLAG_F32OUT | FLAG_SPLITK8, (long)cE * cS, (long)cM * cS, (long)cE * cM, cB * 8);
    kvred_kernel<<<4096, 256, 0, stream>>>(kvp, kvtb);

    // --- att[b] = (pq[b] @ kv[b]) / (den+1e-6) -> X ---
    gemm(Pb, kvtb, nullptr, vec64k, nullptr, attb, cS, cM, cE, cM, cM, 1.f,
         FLAG_DEN, (long)cS * cM, (long)cE * cM, (long)cS * cE, cB);

    // --- a = att @ Wo + bo -> Y ; LN in place ---
    gemm(attb, WoT_i, bo_i, nullptr, nullptr, ab, cNBS, cE, cE, cE, cE, 1.f,
         FLAG_BIAS, 0, 0, 0, 1);
    ln_kernel<<<cNBS, 256, 0, stream>>>(ab, g_i, b_i);

    // --- FFN in 4 row-chunks of 16384; h += ffn(y) ---
    for (int c = 0; c < 4; ++c) {
      const unsigned short* yc = ab + (long)c * 16384 * cE;
      unsigned short* hc = h + (long)c * 16384 * cE;
      gemm(yc, W1T_i, b1_i, nullptr, nullptr, u1b, 16384, cE, cFF, cE, cE, 1.f,
           FLAG_BIAS | FLAG_GELU, 0, 0, 0, 1);
      gemm(u1b, W2T_i, b2_i, nullptr, nullptr, hc, 16384, cFF, cE, cFF, cFF, 1.f,
           FLAG_BIAS | FLAG_RES, 0, 0, 0, 1, hc);
    }
  }

  head_kernel<<<cB, 256, 0, stream>>>(h, Wr1C, br1C, Wr2C, br2C, d_out, dflag);
}